// Round 4
// baseline (168.923 us; speedup 1.0000x reference)
//
#include <hip/hip_runtime.h>

// DWT Haar 2x2 block transform:
//   in : (32, 3, 512, 512) fp32
//   out: (32, 12, 256, 256) fp32, sub-band order per (b,c): LL, LH, HL, HH
//
// v4 (resubmit — previous bench died on container acquisition, not kernel):
// deepen per-wave MLP. Each thread handles TWO row-pairs (output rows
// 2j and 2j+1): all 8 nt loads issued before any use (chunk-1 loads stay
// in flight across chunk-0 compute+stores -> read queue never drains),
// then 8 nt stores. Per wave: 8 KB linear read (input rows 4j..4j+3),
// 2 KB linear per sub-band plane written. Wave count halves (24576->12288).
// VGPR ~56 (<64) keeps full 32-waves/CU occupancy -> peak in-flight
// read bytes/CU doubles. Eliminated axes: VMEM instr shape (v1==v2),
// cache policy (v3 nt: +9%, kept). Arithmetic order identical to v1
// (absmax 0.0).

typedef float v4f __attribute__((ext_vector_type(4)));  // native Clang vector

#define B_   32
#define C_   3
#define H_   512
#define W_   512
#define HO_  (H_/2)          // 256
#define WO_  (W_/2)          // 256
#define WQ_  (W_/8)          // 64 col-quads per output row
#define JQ_  (HO_/2)         // 128 output-row pairs
#define PLANE_ (HO_*WO_)     // 65536 floats per sub-band plane
#define NTHREADS_TOTAL (B_*C_*JQ_*WQ_)   // 786,432

__global__ __launch_bounds__(256) void dwt_haar_kernel(
        const float* __restrict__ x, float* __restrict__ out) {
    int g = blockIdx.x * blockDim.x + threadIdx.x;
    // g = ((bc*128 + j)*64 + wq)
    int wq = g & (WQ_ - 1);
    int t  = g >> 6;
    int j  = t & (JQ_ - 1);        // output row pair: rows 2j, 2j+1
    int bc = t >> 7;               // b*3 + c, 0..95

    // input: 4 rows (4j..4j+3) x 2 v4f each, ALL loads issued up front
    const v4f* row = reinterpret_cast<const v4f*>(
        x + ((size_t)bc * H_ + 4 * (size_t)j) * W_) + 2 * wq;
    const int RS = W_ / 4;         // 128 v4f per input row
    v4f r0a = __builtin_nontemporal_load(row);
    v4f r0b = __builtin_nontemporal_load(row + 1);
    v4f r1a = __builtin_nontemporal_load(row + RS);
    v4f r1b = __builtin_nontemporal_load(row + RS + 1);
    v4f r2a = __builtin_nontemporal_load(row + 2 * RS);
    v4f r2b = __builtin_nontemporal_load(row + 2 * RS + 1);
    v4f r3a = __builtin_nontemporal_load(row + 3 * RS);
    v4f r3b = __builtin_nontemporal_load(row + 3 * RS + 1);

    int b = bc / C_;
    int c = bc - b * C_;
    // output base for row 2j of plane (b, c*4)
    v4f* obase = reinterpret_cast<v4f*>(
        out + (((size_t)b * (C_ * 4) + c * 4) * HO_ + 2 * (size_t)j) * WO_
            + 4 * (size_t)wq);
    const int PS = PLANE_ / 4;     // plane stride in v4f
    const int OR = WO_ / 4;        // output row stride in v4f (64)

    // chunk 0: input rows 4j, 4j+1 -> output row 2j
    {
        v4f LL, LH, HL, HH;
        {   float a = r0a.x, bb = r0a.y, cc = r1a.x, d = r1a.y;
            LL.x = (a + bb + cc + d) * 0.5f;  LH.x = (a + bb - cc - d) * 0.5f;
            HL.x = (a - bb + cc - d) * 0.5f;  HH.x = (a - bb - cc + d) * 0.5f; }
        {   float a = r0a.z, bb = r0a.w, cc = r1a.z, d = r1a.w;
            LL.y = (a + bb + cc + d) * 0.5f;  LH.y = (a + bb - cc - d) * 0.5f;
            HL.y = (a - bb + cc - d) * 0.5f;  HH.y = (a - bb - cc + d) * 0.5f; }
        {   float a = r0b.x, bb = r0b.y, cc = r1b.x, d = r1b.y;
            LL.z = (a + bb + cc + d) * 0.5f;  LH.z = (a + bb - cc - d) * 0.5f;
            HL.z = (a - bb + cc - d) * 0.5f;  HH.z = (a - bb - cc + d) * 0.5f; }
        {   float a = r0b.z, bb = r0b.w, cc = r1b.z, d = r1b.w;
            LL.w = (a + bb + cc + d) * 0.5f;  LH.w = (a + bb - cc - d) * 0.5f;
            HL.w = (a - bb + cc - d) * 0.5f;  HH.w = (a - bb - cc + d) * 0.5f; }
        __builtin_nontemporal_store(LL, obase);
        __builtin_nontemporal_store(LH, obase + PS);
        __builtin_nontemporal_store(HL, obase + 2 * PS);
        __builtin_nontemporal_store(HH, obase + 3 * PS);
    }
    // chunk 1: input rows 4j+2, 4j+3 -> output row 2j+1
    {
        v4f LL, LH, HL, HH;
        {   float a = r2a.x, bb = r2a.y, cc = r3a.x, d = r3a.y;
            LL.x = (a + bb + cc + d) * 0.5f;  LH.x = (a + bb - cc - d) * 0.5f;
            HL.x = (a - bb + cc - d) * 0.5f;  HH.x = (a - bb - cc + d) * 0.5f; }
        {   float a = r2a.z, bb = r2a.w, cc = r3a.z, d = r3a.w;
            LL.y = (a + bb + cc + d) * 0.5f;  LH.y = (a + bb - cc - d) * 0.5f;
            HL.y = (a - bb + cc - d) * 0.5f;  HH.y = (a - bb - cc + d) * 0.5f; }
        {   float a = r2b.x, bb = r2b.y, cc = r3b.x, d = r3b.y;
            LL.z = (a + bb + cc + d) * 0.5f;  LH.z = (a + bb - cc - d) * 0.5f;
            HL.z = (a - bb + cc - d) * 0.5f;  HH.z = (a - bb - cc + d) * 0.5f; }
        {   float a = r2b.z, bb = r2b.w, cc = r3b.z, d = r3b.w;
            LL.w = (a + bb + cc + d) * 0.5f;  LH.w = (a + bb - cc - d) * 0.5f;
            HL.w = (a - bb + cc - d) * 0.5f;  HH.w = (a - bb - cc + d) * 0.5f; }
        v4f* o2 = obase + OR;   // next output row
        __builtin_nontemporal_store(LL, o2);
        __builtin_nontemporal_store(LH, o2 + PS);
        __builtin_nontemporal_store(HL, o2 + 2 * PS);
        __builtin_nontemporal_store(HH, o2 + 3 * PS);
    }
}

extern "C" void kernel_launch(void* const* d_in, const int* in_sizes, int n_in,
                              void* d_out, int out_size, void* d_ws, size_t ws_size,
                              hipStream_t stream) {
    const float* x = (const float*)d_in[0];
    float* out = (float*)d_out;
    dim3 block(256);
    dim3 grid(NTHREADS_TOTAL / 256);   // 3072 blocks
    dwt_haar_kernel<<<grid, block, 0, stream>>>(x, out);
}

// Round 5
// 167.010 us; speedup vs baseline: 1.0115x; 1.0115x over previous
//
#include <hip/hip_runtime.h>

// DWT Haar 2x2 block transform:
//   in : (32, 3, 512, 512) fp32
//   out: (32, 12, 256, 256) fp32, sub-band order per (b,c): LL, LH, HL, HH
//
// v5: persistent-wave, hand-pipelined. 2048 blocks x 256 thr (= 256 CU x 8
// resident blocks, one dispatch round). Each thread handles 3 v1-units at
// stride NTHREADS, straight-line software pipeline:
//   load(u0); load(u1); store(u0); load(u2); store(u1); store(u2)
// so the NEXT unit's 4 nt loads are always in flight while the previous
// unit's 4 nt stores issue — removes the per-wave "loads -> wall -> stores"
// serialization every prior version had (the one structural difference vs
// the 6.29 TB/s grid-stride copy benchmark). Falsified axes: VMEM instr
// shape (v1==v2), cache policy (v3 nt +9%, kept), per-wave load batch depth
// (v4 neutral). Arithmetic order identical to v1 (absmax 0.0).

typedef float v4f __attribute__((ext_vector_type(4)));  // native Clang vector

#define B_   32
#define C_   3
#define H_   512
#define W_   512
#define HO_  (H_/2)          // 256
#define WQ_  (W_/8)          // 64 col-quads per output row
#define PLANE_ (HO_*(W_/2))  // 65536 floats per sub-band plane
#define UNITS_ (B_*C_*HO_*WQ_)   // 1,572,864 v1-units
#define NBLOCKS_ 2048
#define NTHREADS_ (NBLOCKS_*256) // 524,288 -> 3 units/thread exactly

__device__ __forceinline__ const v4f* in_ptr(const float* __restrict__ x, int u) {
    int wq = u & (WQ_ - 1);
    int t  = u >> 6;
    int h  = t & (HO_ - 1);
    int bc = t >> 8;               // b*3 + c, 0..95
    return reinterpret_cast<const v4f*>(
        x + ((size_t)bc * H_ + 2 * (size_t)h) * W_) + 2 * wq;
}

__device__ __forceinline__ v4f* out_ptr(float* __restrict__ out, int u) {
    int wq = u & (WQ_ - 1);
    int t  = u >> 6;
    int h  = t & (HO_ - 1);
    int bc = t >> 8;
    int b  = bc / C_;
    int c  = bc - b * C_;
    return reinterpret_cast<v4f*>(
        out + (((size_t)b * (C_ * 4) + c * 4) * HO_ + h) * (W_ / 2)
            + 4 * (size_t)wq);
}

__device__ __forceinline__ void load_unit(const v4f* p,
        v4f& r0a, v4f& r0b, v4f& r1a, v4f& r1b) {
    const v4f* p1 = p + (W_ / 4);  // next input row
    r0a = __builtin_nontemporal_load(p);
    r0b = __builtin_nontemporal_load(p + 1);
    r1a = __builtin_nontemporal_load(p1);
    r1b = __builtin_nontemporal_load(p1 + 1);
}

__device__ __forceinline__ void compute_store(
        v4f r0a, v4f r0b, v4f r1a, v4f r1b, v4f* obase) {
    v4f LL, LH, HL, HH;
    {   float a = r0a.x, b = r0a.y, c = r1a.x, d = r1a.y;
        LL.x = (a + b + c + d) * 0.5f;  LH.x = (a + b - c - d) * 0.5f;
        HL.x = (a - b + c - d) * 0.5f;  HH.x = (a - b - c + d) * 0.5f; }
    {   float a = r0a.z, b = r0a.w, c = r1a.z, d = r1a.w;
        LL.y = (a + b + c + d) * 0.5f;  LH.y = (a + b - c - d) * 0.5f;
        HL.y = (a - b + c - d) * 0.5f;  HH.y = (a - b - c + d) * 0.5f; }
    {   float a = r0b.x, b = r0b.y, c = r1b.x, d = r1b.y;
        LL.z = (a + b + c + d) * 0.5f;  LH.z = (a + b - c - d) * 0.5f;
        HL.z = (a - b + c - d) * 0.5f;  HH.z = (a - b - c + d) * 0.5f; }
    {   float a = r0b.z, b = r0b.w, c = r1b.z, d = r1b.w;
        LL.w = (a + b + c + d) * 0.5f;  LH.w = (a + b - c - d) * 0.5f;
        HL.w = (a - b + c - d) * 0.5f;  HH.w = (a - b - c + d) * 0.5f; }
    __builtin_nontemporal_store(LL, obase);
    __builtin_nontemporal_store(LH, obase + PLANE_ / 4);
    __builtin_nontemporal_store(HL, obase + 2 * (PLANE_ / 4));
    __builtin_nontemporal_store(HH, obase + 3 * (PLANE_ / 4));
}

__global__ __launch_bounds__(256) void dwt_haar_kernel(
        const float* __restrict__ x, float* __restrict__ out) {
    int tid = blockIdx.x * blockDim.x + threadIdx.x;

    v4f a0, a1, a2, a3;            // stage buffer A
    v4f b0, b1, b2, b3;            // stage buffer B

    // pipeline: L(u0) L(u1) S(u0) L(u2) S(u1) S(u2)
    load_unit(in_ptr(x, tid), a0, a1, a2, a3);
    load_unit(in_ptr(x, tid + NTHREADS_), b0, b1, b2, b3);
    compute_store(a0, a1, a2, a3, out_ptr(out, tid));
    load_unit(in_ptr(x, tid + 2 * NTHREADS_), a0, a1, a2, a3);
    compute_store(b0, b1, b2, b3, out_ptr(out, tid + NTHREADS_));
    compute_store(a0, a1, a2, a3, out_ptr(out, tid + 2 * NTHREADS_));
}

extern "C" void kernel_launch(void* const* d_in, const int* in_sizes, int n_in,
                              void* d_out, int out_size, void* d_ws, size_t ws_size,
                              hipStream_t stream) {
    const float* x = (const float*)d_in[0];
    float* out = (float*)d_out;
    dim3 block(256);
    dim3 grid(NBLOCKS_);           // 2048 blocks, 3 units/thread
    dwt_haar_kernel<<<grid, block, 0, stream>>>(x, out);
}